// Round 4
// baseline (220.839 us; speedup 1.0000x reference)
//
#include <hip/hip_runtime.h>

// GwcVolume: group-wise correlation cost volume.
// left/right: [B, C, H, W] fp32, C = G*CPG (320 = 40*8)
// out: [B, G, D, H, W] fp32
// out[b,g,d,h,w] = (w>=d) ? (1/CPG) * sum_ch L[b,g,ch,h,w]*R[b,g,ch,h,w-d] : 0
//
// Round 4 (= round 3 with the nontemporal-builtin type fix):
//  - clang ext_vector f32x4 instead of HIP float4 (the builtin requires a
//    native vector type).
//  - block = (b,g, 4 h-rows) band; each block processes NB=2 consecutive bands.
//  - Next band's R (32 regs) and L (32 regs) prefetched with nt loads BEFORE
//    the current band's 48-step d-loop -> read latency hides under the store
//    stream; reads/writes interleave smoothly.
//  - LDS [r][w][ch] float8, XOR swizzle f4slot = (2w + half) ^ ((w>>2)&7):
//    conflict-free b128 reads at lane stride 4 in w (round 2: 0 conflicts).
//  - Register sliding window over d: one new R-vec (2 b128) per d-step,
//    d-loop unrolled x4 with register rotation. nt f32x4 stores.

typedef float f32x4 __attribute__((ext_vector_type(4)));

#define BB   2
#define GG   40
#define CPG  8
#define HH   96
#define WW   312
#define HW   (HH * WW)
#define ROWS 4              // h-rows per band
#define W4N  (WW / 4)       // 78 float4-groups per row
#define ACT  (ROWS * W4N)   // 312 active threads
#define NTH  320            // 5 waves
#define F4PR (2 * WW)       // 624 f32x4 slots per LDS row
#define SCALE (1.0f / CPG)
#define NB   2              // bands per block
#define HBLKS (HH / ROWS)   // 24 bands per (b,g)

__global__ __launch_bounds__(NTH) void gwc_volume_kernel(
    const float* __restrict__ left,
    const float* __restrict__ right,
    float* __restrict__ out,
    int D)
{
    __shared__ __align__(16) f32x4 s4[ROWS * F4PR];   // 39936 B -> 4 blocks/CU

    const int t = threadIdx.x;
    const bool active = (t < ACT);
    const int  tt = active ? t : 0;
    const int  r  = tt / W4N;                // h-row within band
    const int  w4 = tt - r * W4N;
    const int  w0 = 4 * w4;

    float  preR[4][8];   // R staging slices (s = t + it*NTH), 8 ch each
    f32x4  preL[8];      // L vec4 per channel for this thread's 4 w's
    float  LJ[4][8];     // active L operands, pre-scaled

    #define BAND_BASE(band, bgv, h0v)                                   \
        const int bgv  = (band) / HBLKS;                                \
        const int h0v  = ((band) % HBLKS) * ROWS;                       \
        const size_t base = (size_t)bgv * CPG * HW + (size_t)h0v * WW;

    #define PREFETCH(band) do {                                         \
        BAND_BASE(band, bg_, h0_)                                       \
        _Pragma("unroll")                                               \
        for (int it = 0; it < 4; ++it) {                                \
            const int s = t + it * NTH;                                 \
            if (s < ROWS * WW) {                                        \
                const float* rp = right + base + s;                     \
                _Pragma("unroll")                                       \
                for (int c = 0; c < CPG; ++c)                           \
                    preR[it][c] = __builtin_nontemporal_load(rp + c * HW); \
            }                                                           \
        }                                                               \
        _Pragma("unroll")                                               \
        for (int c = 0; c < CPG; ++c) {                                 \
            if (active)                                                 \
                preL[c] = __builtin_nontemporal_load(                   \
                    (const f32x4*)(left + base + (size_t)c * HW         \
                                   + (size_t)r * WW + w0));             \
        }                                                               \
    } while (0)

    #define COMMIT() do {                                               \
        _Pragma("unroll")                                               \
        for (int it = 0; it < 4; ++it) {                                \
            const int s = t + it * NTH;                                 \
            if (s < ROWS * WW) {                                        \
                const int rs = s / WW;                                  \
                const int ws = s - rs * WW;                             \
                const int k  = (ws >> 2) & 7;                           \
                const int sl = ((2 * ws) ^ k) + rs * F4PR;              \
                s4[sl]     = (f32x4){preR[it][0], preR[it][1],          \
                                     preR[it][2], preR[it][3]};         \
                s4[sl ^ 1] = (f32x4){preR[it][4], preR[it][5],          \
                                     preR[it][6], preR[it][7]};         \
            }                                                           \
        }                                                               \
        _Pragma("unroll")                                               \
        for (int c = 0; c < CPG; ++c) {                                 \
            LJ[0][c] = preL[c].x * SCALE;                               \
            LJ[1][c] = preL[c].y * SCALE;                               \
            LJ[2][c] = preL[c].z * SCALE;                               \
            LJ[3][c] = preL[c].w * SCALE;                               \
        }                                                               \
    } while (0)

    const int band0 = blockIdx.x * NB;

    PREFETCH(band0);
    COMMIT();
    __syncthreads();

    const f32x4* f4row = s4 + r * F4PR;

    #define RVEC(x, A, B) do {                       \
        int xi_ = (x) < 0 ? 0 : (x);                 \
        int k_  = (xi_ >> 2) & 7;                    \
        int sl_ = (2 * xi_) ^ k_;                    \
        A = f4row[sl_];                              \
        B = f4row[sl_ ^ 1];                          \
    } while (0)

    #define DOT8(j, A, B) (LJ[j][0]*A.x + LJ[j][1]*A.y + LJ[j][2]*A.z + LJ[j][3]*A.w \
                         + LJ[j][4]*B.x + LJ[j][5]*B.y + LJ[j][6]*B.z + LJ[j][7]*B.w)

    #define STEP(A_0,B_0, A_1,B_1, A_2,B_2, A_3,B_3) do {      \
        f32x4 st_;                                             \
        st_.x = (x0     >= 0) ? DOT8(0, A_0, B_0) : 0.0f;      \
        st_.y = (x0 + 1 >= 0) ? DOT8(1, A_1, B_1) : 0.0f;      \
        st_.z = (x0 + 2 >= 0) ? DOT8(2, A_2, B_2) : 0.0f;      \
        st_.w = (x0 + 3 >= 0) ? DOT8(3, A_3, B_3) : 0.0f;      \
        if (active) __builtin_nontemporal_store(st_, (f32x4*)op); \
        op += HW;                                              \
    } while (0)

    for (int ib = 0; ib < NB; ++ib) {
        const int band = band0 + ib;

        // Issue next band's global loads now; they drain under the d-loop.
        if (ib + 1 < NB) {
            PREFETCH(band + 1);
            __builtin_amdgcn_sched_barrier(0);   // pin issue point
        }

        BAND_BASE(band, bg, h0)
        (void)base;

        f32x4 A0,B0, A1,B1, A2,B2, A3,B3;
        RVEC(w0 + 0, A0, B0);
        RVEC(w0 + 1, A1, B1);
        RVEC(w0 + 2, A2, B2);
        RVEC(w0 + 3, A3, B3);

        float* op = out + (size_t)bg * D * HW + (size_t)(h0 + r) * WW + w0;
        int x0 = w0;                       // = w0 - d

        const int nq = D >> 2;
        for (int q = 0; q < nq; ++q) {
            STEP(A0,B0, A1,B1, A2,B2, A3,B3);  RVEC(x0 - 1, A3, B3);  x0 -= 1;
            STEP(A3,B3, A0,B0, A1,B1, A2,B2);  RVEC(x0 - 1, A2, B2);  x0 -= 1;
            STEP(A2,B2, A3,B3, A0,B0, A1,B1);  RVEC(x0 - 1, A1, B1);  x0 -= 1;
            STEP(A1,B1, A2,B2, A3,B3, A0,B0);  RVEC(x0 - 1, A0, B0);  x0 -= 1;
        }

        // remainder for D % 4 != 0 (dead for D=48, kept for safety)
        for (int d = nq * 4; d < D; ++d) {
            const int xb = w0 - d;
            f32x4 Xa, Xb, st_;
            RVEC(xb + 0, Xa, Xb); st_.x = (xb     >= 0) ? DOT8(0, Xa, Xb) : 0.0f;
            RVEC(xb + 1, Xa, Xb); st_.y = (xb + 1 >= 0) ? DOT8(1, Xa, Xb) : 0.0f;
            RVEC(xb + 2, Xa, Xb); st_.z = (xb + 2 >= 0) ? DOT8(2, Xa, Xb) : 0.0f;
            RVEC(xb + 3, Xa, Xb); st_.w = (xb + 3 >= 0) ? DOT8(3, Xa, Xb) : 0.0f;
            if (active) __builtin_nontemporal_store(st_, (f32x4*)op);
            op += HW;
        }

        // Commit the prefetched next band into LDS/registers.
        if (ib + 1 < NB) {
            __syncthreads();     // all waves done reading current LDS band
            COMMIT();
            __syncthreads();
        }
    }

    #undef RVEC
    #undef DOT8
    #undef STEP
    #undef PREFETCH
    #undef COMMIT
    #undef BAND_BASE
}

extern "C" void kernel_launch(void* const* d_in, const int* in_sizes, int n_in,
                              void* d_out, int out_size, void* d_ws, size_t ws_size,
                              hipStream_t stream) {
    const float* left  = (const float*)d_in[0];
    const float* right = (const float*)d_in[1];
    float* out = (float*)d_out;

    // max_disp lives in device memory (d_in[2]); derive D from out_size on host.
    const int D = out_size / (BB * GG * HH * WW);   // = 48

    dim3 grid(BB * GG * HBLKS / NB);    // 960 persistent blocks, 2 bands each
    dim3 block(NTH);                    // 5 waves; 312 active threads
    hipLaunchKernelGGL(gwc_volume_kernel, grid, block, 0, stream,
                       left, right, out, D);
}

// Round 5
// 137.891 us; speedup vs baseline: 1.6015x; 1.6015x over previous
//
#include <hip/hip_runtime.h>

// GwcVolume: group-wise correlation cost volume.
// left/right: [B, C, H, W] fp32, C = G*CPG (320 = 40*8)
// out: [B, G, D, H, W] fp32
// out[b,g,d,h,w] = (w>=d) ? (1/CPG) * sum_ch L[b,g,ch,h,w]*R[b,g,ch,h,w-d] : 0
//
// Round 5 = round-2 frame (140 us, 0 LDS conflicts) with:
//  - vectorized R staging: 8 x f32x4 loads per thread (own 4 columns),
//    in-register transpose, 8 x ds_write_b128 (conflict-free under swizzle).
//    4x fewer staging VMEM insts, no integer divides, full load MLP.
//  - __launch_bounds__(320, 5): cap VGPR at 102 so 5 waves/SIMD are
//    guaranteed -> 20 waves/CU -> 4 blocks/CU (LDS 40KB allows exactly 4).
//    d-loop live set ~90-95 VGPR, fits.
//  - no nontemporal ops, no sched_barrier, no register prefetch
//    (round-4 post-mortem: 64 prefetch VGPRs -> occupancy cliff -> 220 us).
//
// LDS layout [r][w][ch] as f32x4 pairs, XOR swizzle:
//   f4slot = (2w + half) ^ ((w>>2)&7)
// d-loop: register sliding window, 1 new R-vec (2 x ds_read_b128) per d-step,
// unrolled x4 with register rotation; f32x4 stores.

typedef float f32x4 __attribute__((ext_vector_type(4)));

#define BB   2
#define GG   40
#define CPG  8
#define HH   96
#define WW   312
#define HW   (HH * WW)
#define ROWS 4              // h-rows per band
#define W4N  (WW / 4)       // 78 float4-groups per row
#define ACT  (ROWS * W4N)   // 312 active threads
#define NTH  320            // 5 waves
#define F4PR (2 * WW)       // 624 f32x4 slots per LDS row
#define SCALE (1.0f / CPG)

__global__ __launch_bounds__(NTH, 5) void gwc_volume_kernel(
    const float* __restrict__ left,
    const float* __restrict__ right,
    float* __restrict__ out,
    int D)
{
    __shared__ __align__(16) f32x4 s4[ROWS * F4PR];   // 39936 B -> 4 blocks/CU

    const int t   = threadIdx.x;
    const int bid = blockIdx.x;              // = bg*(HH/ROWS) + hblk
    const int hblk = bid % (HH / ROWS);
    const int bg   = bid / (HH / ROWS);
    const int h0   = hblk * ROWS;

    const bool active = (t < ACT);
    const int  tt = active ? t : 0;
    const int  r  = tt / W4N;                // h-row within band
    const int  w4 = tt - r * W4N;
    const int  w0 = 4 * w4;

    // start of (bg, ch=0, h0, 0); rows h0..h0+3 contiguous per channel
    const size_t base = (size_t)bg * CPG * HW + (size_t)h0 * WW;
    const size_t rowoff = base + (size_t)r * WW + w0;

    float LJ[4][8];          // L operands, pre-scaled by 1/CPG

    if (active) {
        // ---- issue all 16 loads (8 R + 8 L) back-to-back: full MLP ----
        f32x4 R[8], L[8];
        #pragma unroll
        for (int c = 0; c < CPG; ++c)
            R[c] = *(const f32x4*)(right + rowoff + (size_t)c * HW);
        #pragma unroll
        for (int c = 0; c < CPG; ++c)
            L[c] = *(const f32x4*)(left + rowoff + (size_t)c * HW);

        // ---- in-register transpose -> 8 swizzled ds_write_b128 ----
        // slot(w0+i, half) = (2*(w0+i) + half) ^ k,  k = w4 & 7
        // (since (w0+i)>>2 == w4 for i in 0..3)
        const int k = w4 & 7;
        f32x4* srow = s4 + r * F4PR;
        #pragma unroll
        for (int i = 0; i < 4; ++i) {
            const int sl = (2 * (w0 + i)) ^ k;
            srow[sl]     = (f32x4){R[0][i], R[1][i], R[2][i], R[3][i]};
            srow[sl ^ 1] = (f32x4){R[4][i], R[5][i], R[6][i], R[7][i]};
        }

        #pragma unroll
        for (int c = 0; c < CPG; ++c) {
            LJ[0][c] = L[c].x * SCALE;
            LJ[1][c] = L[c].y * SCALE;
            LJ[2][c] = L[c].z * SCALE;
            LJ[3][c] = L[c].w * SCALE;
        }
    } else {
        #pragma unroll
        for (int j = 0; j < 4; ++j)
            #pragma unroll
            for (int c = 0; c < CPG; ++c)
                LJ[j][c] = 0.0f;
    }
    __syncthreads();

    const f32x4* f4row = s4 + r * F4PR;

    #define RVEC(x, A, B) do {                       \
        int xi_ = (x) < 0 ? 0 : (x);                 \
        int k_  = (xi_ >> 2) & 7;                    \
        int sl_ = (2 * xi_) ^ k_;                    \
        A = f4row[sl_];                              \
        B = f4row[sl_ ^ 1];                          \
    } while (0)

    #define DOT8(j, A, B) (LJ[j][0]*A.x + LJ[j][1]*A.y + LJ[j][2]*A.z + LJ[j][3]*A.w \
                         + LJ[j][4]*B.x + LJ[j][5]*B.y + LJ[j][6]*B.z + LJ[j][7]*B.w)

    #define STEP(A_0,B_0, A_1,B_1, A_2,B_2, A_3,B_3) do {      \
        f32x4 st_;                                             \
        st_.x = (x0     >= 0) ? DOT8(0, A_0, B_0) : 0.0f;      \
        st_.y = (x0 + 1 >= 0) ? DOT8(1, A_1, B_1) : 0.0f;      \
        st_.z = (x0 + 2 >= 0) ? DOT8(2, A_2, B_2) : 0.0f;      \
        st_.w = (x0 + 3 >= 0) ? DOT8(3, A_3, B_3) : 0.0f;      \
        if (active) *(f32x4*)op = st_;                         \
        op += HW;                                              \
    } while (0)

    // init window: V_j = R[w0+j]  (all indices >= 0)
    f32x4 A0,B0, A1,B1, A2,B2, A3,B3;
    RVEC(w0 + 0, A0, B0);
    RVEC(w0 + 1, A1, B1);
    RVEC(w0 + 2, A2, B2);
    RVEC(w0 + 3, A3, B3);

    float* op = out + (size_t)bg * D * HW + (size_t)(h0 + r) * WW + w0;
    int x0 = w0;                       // = w0 - d

    const int nq = D >> 2;
    for (int q = 0; q < nq; ++q) {
        STEP(A0,B0, A1,B1, A2,B2, A3,B3);  RVEC(x0 - 1, A3, B3);  x0 -= 1;
        STEP(A3,B3, A0,B0, A1,B1, A2,B2);  RVEC(x0 - 1, A2, B2);  x0 -= 1;
        STEP(A2,B2, A3,B3, A0,B0, A1,B1);  RVEC(x0 - 1, A1, B1);  x0 -= 1;
        STEP(A1,B1, A2,B2, A3,B3, A0,B0);  RVEC(x0 - 1, A0, B0);  x0 -= 1;
    }

    // remainder for D % 4 != 0 (dead for D=48, kept for safety)
    for (int d = nq * 4; d < D; ++d) {
        const int xb = w0 - d;
        f32x4 Xa, Xb, st_;
        RVEC(xb + 0, Xa, Xb); st_.x = (xb     >= 0) ? DOT8(0, Xa, Xb) : 0.0f;
        RVEC(xb + 1, Xa, Xb); st_.y = (xb + 1 >= 0) ? DOT8(1, Xa, Xb) : 0.0f;
        RVEC(xb + 2, Xa, Xb); st_.z = (xb + 2 >= 0) ? DOT8(2, Xa, Xb) : 0.0f;
        RVEC(xb + 3, Xa, Xb); st_.w = (xb + 3 >= 0) ? DOT8(3, Xa, Xb) : 0.0f;
        if (active) *(f32x4*)op = st_;
        op += HW;
    }

    #undef RVEC
    #undef DOT8
    #undef STEP
}

extern "C" void kernel_launch(void* const* d_in, const int* in_sizes, int n_in,
                              void* d_out, int out_size, void* d_ws, size_t ws_size,
                              hipStream_t stream) {
    const float* left  = (const float*)d_in[0];
    const float* right = (const float*)d_in[1];
    float* out = (float*)d_out;

    // max_disp lives in device memory (d_in[2]); derive D from out_size on host.
    const int D = out_size / (BB * GG * HH * WW);   // = 48

    dim3 grid(BB * GG * (HH / ROWS));   // 1920 blocks, one per (b,g,4-row band)
    dim3 block(NTH);                    // 5 waves; 312 active threads
    hipLaunchKernelGGL(gwc_volume_kernel, grid, block, 0, stream,
                       left, right, out, D);
}